// Round 11
// baseline (781.696 us; speedup 1.0000x reference)
//
#include <hip/hip_runtime.h>
#include <cstddef>
#include <cstdint>

typedef unsigned short ushort_t;
typedef unsigned char  u8_t;
typedef __attribute__((ext_vector_type(4))) float f32x4;
typedef __attribute__((ext_vector_type(8))) short bf16x8;

#define BB   8192
#define AA   16
#define BA   131072

// ---------------------------------------------------------------------------
// bf16 / fp8 helpers
// ---------------------------------------------------------------------------
__device__ __forceinline__ float bf2f(ushort_t u) {
    union { float f; uint32_t i; } v; v.i = ((uint32_t)u) << 16; return v.f;
}
__device__ __forceinline__ ushort_t f2bf(float f) {
    union { float f; uint32_t i; } v; v.f = f;
    uint32_t r = v.i + 0x7fffu + ((v.i >> 16) & 1u);
    return (ushort_t)(r >> 16);
}
// f32 -> OCP e4m3fn, round-nearest-even, saturating (no inf in fn)
__device__ __forceinline__ u8_t f2e4m3(float f) {
    union { float f; uint32_t u; } v; v.f = f;
    uint32_t s = (v.u >> 24) & 0x80u;
    float a = fabsf(f);
    if (a >= 448.f) return (u8_t)(s | 0x7Eu);          // saturate to 448
    union { float f; uint32_t u; } w; w.f = a;
    int E = (int)(w.u >> 23) - 127;                    // floor(log2 a)
    if (E < -6) E = -6;
    union { uint32_t u; float f; } qs; qs.u = (uint32_t)(127 + 3 - E) << 23; // 2^(3-E)
    int m = (int)rintf(a * qs.f);                      // in [0..16]
    if (m >= 16) { m >>= 1; ++E; if (E > 8) return (u8_t)(s | 0x7Eu); }
    if (m >= 8)  return (u8_t)(s | ((uint32_t)(E + 7) << 3) | (uint32_t)(m - 8));
    return (u8_t)(s | (uint32_t)m);                    // subnormal (E==-6)
}
__device__ __forceinline__ void gload_lds16(const void* g, void* l) {
    __builtin_amdgcn_global_load_lds(
        (const __attribute__((address_space(1))) uint32_t*)g,
        (__attribute__((address_space(3))) uint32_t*)l, 16, 0, 0);
}

// ---------------------------------------------------------------------------
// fp8 8-phase-style 256x256 GEMM, BK=64, 2 bufs x 32KB = 64KB LDS.
// Per tile t: 4 quadrant phases. q0: vmcnt(0)+bar, read all B frags (b64),
// burst-stage ALL of tile t+1 (4 gloads/thread -> 4-phase latency cover),
// then per phase 2 A-frag rows, 16x MFMA fp8 (2m x 4n x 2kk), end barrier.
// LDS layout (line-paired): line l (128B, 8 granules of 16B) holds rows
// 2l,2l+1 (64B each); granule g: row 2l+(g>>2), colbytes (g&3)*16; stored at
// phys p = g ^ (l&7). ds_read_b64 achieves structural-minimum bank usage.
// A: k<ksplit from A(lda bytes) else A2(lda2); Bt [N][K] fp8; C fp8 out
// (+bias f32, opt relu), row stride ldc bytes. Grid: XCD-panel swizzle.
// ---------------------------------------------------------------------------
template<bool RELU>
__global__ __launch_bounds__(512, 2)
void gemm8p_fp8(const u8_t* __restrict__ A, int lda,
                const u8_t* __restrict__ A2, int lda2, int ksplit,
                const u8_t* __restrict__ Bt,
                const float* __restrict__ bias,
                u8_t* __restrict__ C, int ldc, int K, int lgx, int rpx)
{
    __shared__ u8_t lds[65536];        // 2 bufs x (A 16384 + B 16384) bytes

    const int tid  = threadIdx.x;
    const int w    = tid >> 6;
    const int lane = tid & 63;
    const int wm   = w >> 2;
    const int wn   = w & 3;
    const int fr   = lane & 15;
    const int fq   = lane >> 4;

    const int bid  = blockIdx.x;
    const int xcd  = bid & 7;
    const int slot = bid >> 3;
    const int x    = slot & ((1 << lgx) - 1);
    const int y    = xcd * rpx + (slot >> lgx);
    const size_t brow = (size_t)y * 256;
    const int    bcol = x * 256;

    const int NT = K >> 6;

    f32x4 acc[8][4];
#pragma unroll
    for (int m = 0; m < 8; ++m)
#pragma unroll
        for (int n = 0; n < 4; ++n) acc[m][n] = (f32x4){0.f, 0.f, 0.f, 0.f};

    // precomputed staging sources: j=0,1 -> A granules tid, tid+512;
    //                              j=0,1 -> B granules tid, tid+512.
    size_t aoff[2], a2off[2], boff[2];
    int aldso[2], bldso[2];
#pragma unroll
    for (int j = 0; j < 2; ++j) {
        const int r = tid + (j << 9);           // 0..1023
        const int l = r >> 3;                   // line 0..127
        const int p = r & 7;                    // phys granule
        const int g = p ^ (l & 7);              // logical granule
        const int row  = 2 * l + (g >> 2);
        const int colb = (g & 3) * 16;
        aoff[j]  = (brow + row) * (size_t)lda  + colb;
        a2off[j] = (brow + row) * (size_t)lda2 + colb;
        boff[j]  = (size_t)(bcol + row) * K + colb;
        aldso[j] = r * 16;
        bldso[j] = 16384 + r * 16;
    }

    auto stage_tile = [&](int T) {
        const int k0   = T << 6;
        const int base = (T & 1) << 15;
        const bool hi  = (k0 >= ksplit);
#pragma unroll
        for (int j = 0; j < 2; ++j) {
            const u8_t* src = hi ? (A2 + a2off[j] + (k0 - ksplit))
                                 : (A  + aoff[j]  + k0);
            gload_lds16(src, &lds[base + aldso[j]]);
        }
#pragma unroll
        for (int j = 0; j < 2; ++j)
            gload_lds16(Bt + boff[j] + k0, &lds[base + bldso[j]]);
    };

    stage_tile(0);

    unsigned long breg[4][2];

    for (int t = 0; t < NT; ++t) {
        const int base = (t & 1) << 15;
#pragma unroll
        for (int q = 0; q < 4; ++q) {
            if (q == 0) {
                asm volatile("s_waitcnt vmcnt(0)" ::: "memory");
                __builtin_amdgcn_sched_barrier(0);
                __builtin_amdgcn_s_barrier();
                // all B frags of this tile -> regs
#pragma unroll
                for (int n = 0; n < 4; ++n)
#pragma unroll
                    for (int kk = 0; kk < 2; ++kk) {
                        const int row  = wn * 64 + n * 16 + fr;
                        const int l    = row >> 1;
                        const int slotq = kk * 2 + (fq >> 1);
                        const int g    = (row & 1) * 4 + slotq;
                        const int p    = g ^ (l & 7);
                        const int addr = base + 16384 + l * 128 + p * 16 + (fq & 1) * 8;
                        breg[n][kk] = *(const unsigned long*)&lds[addr];
                    }
                if (t + 1 < NT) stage_tile(t + 1);   // burst: 4-phase cover
            }
            unsigned long areg[2][2];
#pragma unroll
            for (int j = 0; j < 2; ++j)
#pragma unroll
                for (int kk = 0; kk < 2; ++kk) {
                    const int row  = wm * 128 + (2 * q + j) * 16 + fr;
                    const int l    = row >> 1;
                    const int slotq = kk * 2 + (fq >> 1);
                    const int g    = (row & 1) * 4 + slotq;
                    const int p    = g ^ (l & 7);
                    const int addr = base + l * 128 + p * 16 + (fq & 1) * 8;
                    areg[j][kk] = *(const unsigned long*)&lds[addr];
                }
            __builtin_amdgcn_s_setprio(1);
#pragma unroll
            for (int j = 0; j < 2; ++j)
#pragma unroll
                for (int n = 0; n < 4; ++n)
#pragma unroll
                    for (int kk = 0; kk < 2; ++kk)
                        acc[2*q+j][n] = __builtin_amdgcn_mfma_f32_16x16x32_fp8_fp8(
                            (long)areg[j][kk], (long)breg[n][kk], acc[2*q+j][n], 0, 0, 0);
            __builtin_amdgcn_s_setprio(0);
            __builtin_amdgcn_s_barrier();
        }
    }

    // epilogue: C/D layout col=lane&15, row=(lane>>4)*4+r ; fp8 out
#pragma unroll
    for (int m = 0; m < 8; ++m) {
        const size_t rowb = brow + wm * 128 + m * 16 + fq * 4;
#pragma unroll
        for (int n = 0; n < 4; ++n) {
            const int col = bcol + wn * 64 + n * 16 + fr;
            const float bv = bias[col];
#pragma unroll
            for (int r = 0; r < 4; ++r) {
                float v = acc[m][n][r] + bv;
                if (RELU) v = fmaxf(v, 0.f);
                C[(rowb + r) * (size_t)ldc + col] = f2e4m3(v);
            }
        }
    }
}

// ---------------------------------------------------------------------------
// fp8 128x128 GEMM with fused MSE+softmax epilogue (diff GEMM -> iimp).
// Linear LDS layout (conflicts accepted; bytes halved vs bf16). N=128, bcol=0.
// ---------------------------------------------------------------------------
__global__ __launch_bounds__(256)
void gemm_mfma_fp8_mse(const u8_t* __restrict__ A, int lda,
                       const u8_t* __restrict__ A2, int lda2, int ksplit,
                       const u8_t* __restrict__ Bt,
                       const float* __restrict__ bias,
                       int K, float* __restrict__ iimp_out)
{
    __shared__ u8_t As[2][8192];
    __shared__ u8_t Bs[2][8192];

    const int tid  = threadIdx.x;
    const int w    = tid >> 6;
    const int lane = tid & 63;
    const int wm   = w >> 1;
    const int wn   = w & 1;

    const int bid  = blockIdx.x;
    const int xcd  = bid & 7;
    const int slot = bid >> 3;
    const int y    = xcd * 128 + slot;
    const size_t brow = (size_t)y * 128;

    const int fr = lane & 15;
    const int fq = lane >> 4;

    f32x4 acc[4][4];
#pragma unroll
    for (int i = 0; i < 4; ++i)
#pragma unroll
        for (int j = 0; j < 4; ++j) acc[i][j] = (f32x4){0.f, 0.f, 0.f, 0.f};

    const int NT = K >> 6;

    auto stage = [&](int buf, int k0) {
#pragma unroll
        for (int j = 0; j < 2; ++j) {
            const int gi  = tid + (j << 8);     // 0..511
            const int row = gi >> 2;
            const int cb  = (gi & 3) * 16;
            const u8_t* asrc;
            if (k0 >= ksplit)
                asrc = A2 + (brow + row) * (size_t)lda2 + (k0 - ksplit) + cb;
            else
                asrc = A  + (brow + row) * (size_t)lda  + k0 + cb;
            gload_lds16(asrc, &As[buf][gi * 16]);
            gload_lds16(Bt + (size_t)row * K + k0 + cb, &Bs[buf][gi * 16]);
        }
    };

    stage(0, 0);
    __syncthreads();

    for (int t = 0; t < NT; ++t) {
        const int cur = t & 1;
        if (t + 1 < NT) stage(cur ^ 1, (t + 1) << 6);
#pragma unroll
        for (int kk = 0; kk < 2; ++kk) {
            unsigned long a[4], b[4];
#pragma unroll
            for (int f = 0; f < 4; ++f) {
                a[f] = *(const unsigned long*)&As[cur][(wm * 64 + f * 16 + fr) * 64 + kk * 32 + fq * 8];
                b[f] = *(const unsigned long*)&Bs[cur][(wn * 64 + f * 16 + fr) * 64 + kk * 32 + fq * 8];
            }
#pragma unroll
            for (int fm = 0; fm < 4; ++fm)
#pragma unroll
                for (int fn = 0; fn < 4; ++fn)
                    acc[fm][fn] = __builtin_amdgcn_mfma_f32_16x16x32_fp8_fp8(
                        (long)a[fm], (long)b[fn], acc[fm][fn], 0, 0, 0);
        }
        __syncthreads();
    }

    // MSE epilogue: per-row sumsq of (acc+bias) -> per-16-row softmax -> iimp
    float* rowsq = (float*)As;
    if (tid < 128) rowsq[tid] = 0.f;
    __syncthreads();
#pragma unroll
    for (int fm = 0; fm < 4; ++fm) {
#pragma unroll
        for (int r = 0; r < 4; ++r) {
            float s = 0.f;
#pragma unroll
            for (int fn = 0; fn < 4; ++fn) {
                const int col = wn * 64 + fn * 16 + fr;
                const float v = acc[fm][fn][r] + bias[col];
                s += v * v;
            }
            s += __shfl_xor(s, 1);
            s += __shfl_xor(s, 2);
            s += __shfl_xor(s, 4);
            s += __shfl_xor(s, 8);
            if (fr == 0)
                atomicAdd(&rowsq[wm * 64 + fm * 16 + fq * 4 + r], s);
        }
    }
    __syncthreads();
    if (tid < 8) {
        const int rb = tid * 16;
        float mv[16], mx = -1e30f;
#pragma unroll
        for (int a = 0; a < 16; ++a) {
            mv[a] = rowsq[rb + a] * (1.f / 128.f);
            mx = fmaxf(mx, mv[a]);
        }
        float e[16], den = 0.f;
#pragma unroll
        for (int a = 0; a < 16; ++a) { e[a] = __expf(mv[a] - mx); den += e[a]; }
        const float inv = 1.f / den;
        const size_t b = brow / 16 + tid;
#pragma unroll
        for (int a = 0; a < 16; ++a) iimp_out[b * 16 + a] = e[a] * inv;
    }
}

// ---------------------------------------------------------------------------
// bf16 8-phase 256x256 GEMM (round-10 kernel, verified) — used for combine
// with FUSE_OUT=true (fused output head).
// ---------------------------------------------------------------------------
template<bool RELU, bool FUSE_OUT>
__global__ __launch_bounds__(512, 2)
void gemm8p(const ushort_t* __restrict__ A, int lda,
            const ushort_t* __restrict__ A2, int lda2, int ksplit,
            const ushort_t* __restrict__ Bt,
            const float* __restrict__ bias,
            ushort_t* __restrict__ C, int ldc, int K, int lgx, int rpx,
            const ushort_t* __restrict__ W2t, const float* __restrict__ b2)
{
    __shared__ ushort_t lds[65536];

    const int tid  = threadIdx.x;
    const int w    = tid >> 6;
    const int lane = tid & 63;
    const int wm   = w >> 2;
    const int wn   = w & 3;
    const int fr   = lane & 15;
    const int fq   = lane >> 4;

    const int bid  = blockIdx.x;
    const int xcd  = bid & 7;
    const int slot = bid >> 3;
    const int x    = slot & ((1 << lgx) - 1);
    const int y    = xcd * rpx + (slot >> lgx);
    const size_t brow = (size_t)y * 256;
    const int    bcol = x * 256;

    const int NT = K >> 6;
    const int NI = NT >> 1;

    const int srl = tid >> 3;
    const int spg = tid & 7;

    f32x4 acc[8][4];
#pragma unroll
    for (int m = 0; m < 8; ++m)
#pragma unroll
        for (int n = 0; n < 4; ++n) acc[m][n] = (f32x4){0.f, 0.f, 0.f, 0.f};

    const ushort_t* aB1[4];
    const ushort_t* aB2[4];
    const ushort_t* bB[4];
    int ldsA[4], ldsB[4];
#pragma unroll
    for (int s = 0; s < 4; ++s) {
        const int rowA = (srl < 32) ? s * 32 + srl : 128 + s * 32 + (srl - 32);
        const int colA = ((spg ^ (rowA & 7)) << 3);
        aB1[s] = A  + (brow + rowA) * (size_t)lda  + colA;
        aB2[s] = A2 + (brow + rowA) * (size_t)lda2 + colA - ksplit;
        ldsA[s] = rowA * 64 + spg * 8;
        const int rowB = s * 64 + srl;
        const int colB = ((spg ^ (rowB & 7)) << 3);
        bB[s]   = Bt + (size_t)(bcol + rowB) * K + colB;
        ldsB[s] = 16384 + rowB * 64 + spg * 8;
    }

    auto stageA = [&](int T, int s, int bi) {
        const int k0 = T << 6;
        const ushort_t* src = (k0 >= ksplit ? aB2[s] : aB1[s]) + k0;
        gload_lds16(src, &lds[(bi << 15) + ldsA[s]]);
    };
    auto stageB = [&](int T, int c, int bi) {
        gload_lds16(bB[c] + (T << 6), &lds[(bi << 15) + ldsB[c]]);
    };

    stageA(0, 0, 0); stageB(0, 0, 0);
    stageA(0, 1, 0); stageB(0, 1, 0);
    stageA(0, 2, 0); stageB(0, 2, 0);
    stageA(0, 3, 0); stageB(0, 3, 0);
    stageA(1, 0, 1); stageB(1, 0, 1);
    stageA(1, 1, 1); stageB(1, 1, 1);
    stageA(1, 2, 1); stageB(1, 2, 1);

    bf16x8 breg[4][2];

    for (int i = 0; i < NI; ++i) {
        const bool more = (i + 1 < NI);
#pragma unroll
        for (int h = 0; h < 2; ++h) {
            const int bufA = h << 15;
            const int bufB = (h << 15) + 16384;
#pragma unroll
            for (int q = 0; q < 4; ++q) {
                if (q == 0) {
                    if (h == 0 || more) asm volatile("s_waitcnt vmcnt(6)" ::: "memory");
                    else                asm volatile("s_waitcnt vmcnt(0)" ::: "memory");
                    __builtin_amdgcn_sched_barrier(0);
                    __builtin_amdgcn_s_barrier();
#pragma unroll
                    for (int n = 0; n < 4; ++n)
#pragma unroll
                        for (int kk = 0; kk < 2; ++kk) {
                            const int row = wn * 64 + n * 16 + fr;
                            const int gp  = ((kk * 4 + fq) ^ (row & 7)) << 3;
                            breg[n][kk] = *(const bf16x8*)&lds[bufB + row * 64 + gp];
                        }
                }
                bf16x8 areg[2][2];
#pragma unroll
                for (int j = 0; j < 2; ++j)
#pragma unroll
                    for (int kk = 0; kk < 2; ++kk) {
                        const int row = wm * 128 + (2 * q + j) * 16 + fr;
                        const int gp  = ((kk * 4 + fq) ^ (row & 7)) << 3;
                        areg[j][kk] = *(const bf16x8*)&lds[bufA + row * 64 + gp];
                    }
                if (h == 0) {
                    if (q == 0)      { stageA(2*i+1, 3, 1); stageB(2*i+1, 3, 1); }
                    else if (more)   { stageA(2*i+2, q-1, 0); stageB(2*i+2, q-1, 0); }
                } else {
                    if (q == 0) { if (more) { stageA(2*i+2, 3, 0); stageB(2*i+2, 3, 0); } }
                    else        { if (more) { stageA(2*i+3, q-1, 1); stageB(2*i+3, q-1, 1); } }
                }
                __builtin_amdgcn_s_setprio(1);
#pragma unroll
                for (int j = 0; j < 2; ++j)
#pragma unroll
                    for (int n = 0; n < 4; ++n)
#pragma unroll
                        for (int kk = 0; kk < 2; ++kk)
                            acc[2*q+j][n] = __builtin_amdgcn_mfma_f32_16x16x32_bf16(
                                areg[j][kk], breg[n][kk], acc[2*q+j][n], 0, 0, 0);
                __builtin_amdgcn_s_setprio(0);
                __builtin_amdgcn_s_barrier();
            }
        }
    }

    if (!FUSE_OUT) {
#pragma unroll
        for (int m = 0; m < 8; ++m) {
            const size_t rowb = brow + wm * 128 + m * 16 + fq * 4;
#pragma unroll
            for (int n = 0; n < 4; ++n) {
                const int col = bcol + wn * 64 + n * 16 + fr;
                const float bv = bias[col];
#pragma unroll
                for (int r = 0; r < 4; ++r) {
                    float v = acc[m][n][r] + bv;
                    if (RELU) v = fmaxf(v, 0.f);
                    C[(rowb + r) * (size_t)ldc + col] = f2bf(v);
                }
            }
        }
    } else {
#pragma unroll
        for (int m = 0; m < 8; ++m) {
            const int row = wm * 128 + m * 16 + fq * 4;
#pragma unroll
            for (int n = 0; n < 4; ++n) {
                const int col = wn * 64 + n * 16 + fr;
                const float bv = bias[col];
#pragma unroll
                for (int r = 0; r < 4; ++r) {
                    const float v = fmaxf(acc[m][n][r] + bv, 0.f);
                    const int rr = row + r;
                    const int g  = (col >> 3) ^ (rr & 7);
                    lds[rr * 256 + g * 8 + (col & 7)] = f2bf(v);
                }
            }
        }
        bf16x8 w2f[4][8];
#pragma unroll
        for (int n2 = 0; n2 < 4; ++n2)
#pragma unroll
            for (int kk = 0; kk < 8; ++kk)
                w2f[n2][kk] = *(const bf16x8*)&W2t[(n2 * 16 + fr) * 256 + kk * 32 + fq * 8];
        __syncthreads();
        f32x4 acc2[2][4];
#pragma unroll
        for (int m2 = 0; m2 < 2; ++m2)
#pragma unroll
            for (int n2 = 0; n2 < 4; ++n2) acc2[m2][n2] = (f32x4){0.f, 0.f, 0.f, 0.f};
#pragma unroll
        for (int kk = 0; kk < 8; ++kk) {
#pragma unroll
            for (int m2 = 0; m2 < 2; ++m2) {
                const int row = w * 32 + m2 * 16 + fr;
                const int g   = (kk * 4 + fq) ^ (row & 7);
                const bf16x8 af = *(const bf16x8*)&lds[row * 256 + g * 8];
#pragma unroll
                for (int n2 = 0; n2 < 4; ++n2)
                    acc2[m2][n2] = __builtin_amdgcn_mfma_f32_16x16x32_bf16(
                        af, w2f[n2][kk], acc2[m2][n2], 0, 0, 0);
            }
        }
        float* outp = (float*)C;
#pragma unroll
        for (int m2 = 0; m2 < 2; ++m2) {
            const size_t rowb = brow + w * 32 + m2 * 16 + fq * 4;
#pragma unroll
            for (int n2 = 0; n2 < 4; ++n2) {
                const int col = n2 * 16 + fr;
                const float bv = b2[col];
#pragma unroll
                for (int r = 0; r < 4; ++r)
                    outp[(rowb + r) * 64 + col] = acc2[m2][n2][r] + bv;
            }
        }
    }
}

// ---------------------------------------------------------------------------
// bf16 128x128 GEMM (proven) — used for kvq.
// ---------------------------------------------------------------------------
__global__ __launch_bounds__(256)
void gemm_mfma(const ushort_t* __restrict__ A, int lda,
               const ushort_t* __restrict__ Bt,
               const float* __restrict__ bias,
               ushort_t* __restrict__ C, int ldc, int N, int K, int lgx)
{
    __shared__ ushort_t As[2][128 * 64];
    __shared__ ushort_t Bs[2][128 * 64];

    const int tid  = threadIdx.x;
    const int w    = tid >> 6;
    const int lane = tid & 63;
    const int wm   = w >> 1;
    const int wn   = w & 1;

    const int bid  = blockIdx.x;
    const int xcd  = bid & 7;
    const int slot = bid >> 3;
    const int x    = slot & ((1 << lgx) - 1);
    const int y    = xcd * 128 + (slot >> lgx);
    const size_t brow = (size_t)y * 128;
    const int    bcol = x * 128;

    const int fr   = lane & 15;
    const int fq   = lane >> 4;
    const int srow = lane >> 3;
    const int scol = (lane & 7) << 3;

    f32x4 acc[4][4];
#pragma unroll
    for (int i = 0; i < 4; ++i)
#pragma unroll
        for (int j = 0; j < 4; ++j) acc[i][j] = (f32x4){0.f, 0.f, 0.f, 0.f};

    const int NT = K >> 6;

    auto stage = [&](int buf, int k0) {
#pragma unroll
        for (int i = 0; i < 4; ++i) {
            const int c = (w << 2) + i;
            const int r = (c << 3) + srow;
            gload_lds16(A + (brow + r) * (size_t)lda + k0 + scol,
                        &As[buf][(c << 9) + lane * 8]);
            gload_lds16(Bt + (size_t)(bcol + r) * K + k0 + scol,
                        &Bs[buf][(c << 9) + lane * 8]);
        }
    };

    stage(0, 0);
    __syncthreads();

    for (int t = 0; t < NT; ++t) {
        const int cur = t & 1;
        if (t + 1 < NT) stage(cur ^ 1, (t + 1) << 6);
#pragma unroll
        for (int kk = 0; kk < 2; ++kk) {
            bf16x8 a[4], b[4];
#pragma unroll
            for (int f = 0; f < 4; ++f) {
                a[f] = *(const bf16x8*)&As[cur][(wm * 64 + f * 16 + fr) * 64 + kk * 32 + fq * 8];
                b[f] = *(const bf16x8*)&Bs[cur][(wn * 64 + f * 16 + fr) * 64 + kk * 32 + fq * 8];
            }
#pragma unroll
            for (int fm = 0; fm < 4; ++fm)
#pragma unroll
                for (int fn = 0; fn < 4; ++fn)
                    acc[fm][fn] = __builtin_amdgcn_mfma_f32_16x16x32_bf16(
                        a[fm], b[fn], acc[fm][fn], 0, 0, 0);
        }
        __syncthreads();
    }

#pragma unroll
    for (int fm = 0; fm < 4; ++fm) {
        const size_t rowb = brow + wm * 64 + fm * 16 + fq * 4;
#pragma unroll
        for (int fn = 0; fn < 4; ++fn) {
            const int col = bcol + wn * 64 + fn * 16 + fr;
            if (col < N) {
                const float bv = bias[col];
#pragma unroll
                for (int r = 0; r < 4; ++r)
                    C[(rowb + r) * (size_t)ldc + col] = f2bf(acc[fm][fn][r] + bv);
            }
        }
    }
}

// ---------------------------------------------------------------------------
// prep kernels
// ---------------------------------------------------------------------------
__global__ __launch_bounds__(256)
void transpose_w(const float* __restrict__ W, ushort_t* __restrict__ Wt,
                 int K, int N, int Npad)
{
    int idx = blockIdx.x * 256 + threadIdx.x;
    if (idx >= Npad * K) return;
    int n = idx / K, k = idx - n * K;
    float v = (n < N) ? W[(size_t)k * N + n] : 0.f;
    Wt[idx] = f2bf(v);
}

__global__ __launch_bounds__(256)
void transpose_w_fp8(const float* __restrict__ W, u8_t* __restrict__ Wt,
                     int K, int N, int Npad)
{
    int idx = blockIdx.x * 256 + threadIdx.x;
    if (idx >= Npad * K) return;
    int n = idx / K, k = idx - n * K;
    float v = (n < N) ? W[(size_t)k * N + n] : 0.f;
    Wt[idx] = f2e4m3(v);
}

__global__ __launch_bounds__(256)
void transpose_wk_fp8(const float* __restrict__ W, u8_t* __restrict__ Wt,
                      int Ksrc, int N, int ldk, int kOff, float sign)
{
    int idx = blockIdx.x * 256 + threadIdx.x;
    if (idx >= N * Ksrc) return;
    int n = idx / Ksrc, k = idx - n * Ksrc;
    Wt[(size_t)n * ldk + kOff + k] = f2e4m3(sign * W[(size_t)k * N + n]);
}

__global__ __launch_bounds__(256)
void conv_f32_bf16(const float* __restrict__ src, ushort_t* __restrict__ dst)
{
    size_t q = (size_t)blockIdx.x * 256 + threadIdx.x;
    float4 v = ((const float4*)src)[q];
    ushort_t* d = dst + q * 4;
    d[0] = f2bf(v.x); d[1] = f2bf(v.y); d[2] = f2bf(v.z); d[3] = f2bf(v.w);
}

__global__ __launch_bounds__(256)
void conv_f32_fp8(const float* __restrict__ src, u8_t* __restrict__ dst)
{
    size_t q = (size_t)blockIdx.x * 256 + threadIdx.x;
    float4 v = ((const float4*)src)[q];
    uint32_t pk = (uint32_t)f2e4m3(v.x) | ((uint32_t)f2e4m3(v.y) << 8) |
                  ((uint32_t)f2e4m3(v.z) << 16) | ((uint32_t)f2e4m3(v.w) << 24);
    ((uint32_t*)dst)[q] = pk;
}

__global__ void pack_cat2(const float* __restrict__ a, const float* __restrict__ b,
                          float* __restrict__ o)
{
    int j = blockIdx.x * 256 + threadIdx.x;
    if (j < 512) o[j] = a[j];
    else if (j < 1024) o[j] = b[j - 512];
}

__global__ void pack_bias(const float* __restrict__ bk, const float* __restrict__ bq,
                          const float* __restrict__ bv, float* __restrict__ pb)
{
    int j = threadIdx.x;
    float v = 0.f;
    if      (j < 32)  v = bk[j];
    else if (j < 64)  v = bq[j - 32];
    else if (j < 192) v = bv[j - 64];
    pb[j] = v;
}

__global__ void make_cbias(const float* __restrict__ bt2, const float* __restrict__ bp3,
                           float* __restrict__ cb)
{
    int j = threadIdx.x;
    cb[j] = bt2[j] - bp3[j];
}

// ---------------------------------------------------------------------------
// attention: kvq packed [BA][192] bf16; writes applied [BA][128] bf16.
// ---------------------------------------------------------------------------
__global__ __launch_bounds__(256)
void attn_apply(const ushort_t* __restrict__ kvq, const float* __restrict__ Wa,
                const float* __restrict__ ba, const float* __restrict__ iimp,
                ushort_t* __restrict__ applied)
{
    const int b = blockIdx.x, t = threadIdx.x;
    __shared__ float klds[512], qlds[512];
    __shared__ ushort_t vlds[2048];
    __shared__ float part[16][17];
    __shared__ float kp[16];
    __shared__ float attn[16][17];

    for (int i = t; i < 512; i += 256) {
        int a = i >> 5, c = i & 31;
        const size_t base = ((size_t)b * AA + a) * 192;
        klds[i] = bf2f(kvq[base + c]);
        qlds[i] = bf2f(kvq[base + 32 + c]);
    }
    for (int i = t; i < 2048; i += 256) {
        int j = i >> 7, v = i & 127;
        vlds[i] = kvq[((size_t)b * AA + j) * 192 + 64 + v];
    }
    __syncthreads();

    {
        int j = t & 15, seg = t >> 4;
        float s = 0.f;
        for (int c = seg * 32; c < seg * 32 + 32; ++c)
            s += klds[c] * Wa[(32 + c) * 16 + j];
        part[j][seg] = s;
    }
    __syncthreads();
    if (t < 16) {
        float s = 0.f;
#pragma unroll
        for (int seg = 0; seg < 16; ++seg) s += part[t][seg];
        kp[t] = s;
    }
    __syncthreads();

    {
        int i = t >> 4, j = t & 15;
        float s = 0.f;
#pragma unroll
        for (int q = 0; q < 32; ++q) s += qlds[i * 32 + q] * Wa[q * 16 + j];
        attn[i][j] = s + kp[j] + ba[j];
    }
    __syncthreads();
    if (t < 16) {
        float mx = -1e30f;
#pragma unroll
        for (int j = 0; j < 16; ++j) mx = fmaxf(mx, attn[t][j]);
        float e[16], den = 0.f;
#pragma unroll
        for (int j = 0; j < 16; ++j) { e[j] = __expf(attn[t][j] - mx); den += e[j]; }
        float inv = 1.f / den;
#pragma unroll
        for (int j = 0; j < 16; ++j)
            attn[t][j] = e[j] * inv + 0.5f * iimp[b * 16 + j];
    }
    __syncthreads();

    for (int o = t; o < 2048; o += 256) {
        int i = o >> 7, v = o & 127;
        float s = 0.f;
#pragma unroll
        for (int j = 0; j < 16; ++j) s += attn[i][j] * bf2f(vlds[j * 128 + v]);
        applied[((size_t)b * AA + i) * 128 + v] = f2bf(s);
    }
}

// ---------------------------------------------------------------------------
// launch
// ---------------------------------------------------------------------------
extern "C" void kernel_launch(void* const* d_in, const int* in_sizes, int n_in,
                              void* d_out, int out_size, void* d_ws, size_t ws_size,
                              hipStream_t stream)
{
    const float* x      = (const float*)d_in[0];
    const float* hidden = (const float*)d_in[1];
    const float* Wk  = (const float*)d_in[2];
    const float* bk  = (const float*)d_in[3];
    const float* Wv  = (const float*)d_in[4];
    const float* bv  = (const float*)d_in[5];
    const float* Wq  = (const float*)d_in[6];
    const float* bq  = (const float*)d_in[7];
    const float* Wa  = (const float*)d_in[8];
    const float* ba  = (const float*)d_in[9];
    const float* Wt1 = (const float*)d_in[10];
    const float* bt1 = (const float*)d_in[11];
    const float* Wt2 = (const float*)d_in[12];
    const float* bt2 = (const float*)d_in[13];
    const float* Wp1 = (const float*)d_in[14];
    const float* bp1 = (const float*)d_in[15];
    const float* Wp2 = (const float*)d_in[16];
    const float* bp2 = (const float*)d_in[17];
    const float* Wp3 = (const float*)d_in[18];
    const float* bp3 = (const float*)d_in[19];
    const float* Wc  = (const float*)d_in[20];
    const float* bc  = (const float*)d_in[21];
    const float* W2  = (const float*)d_in[22];
    const float* b2  = (const float*)d_in[23];

    float* out = (float*)d_out;
    u8_t*  ws8 = (u8_t*)d_ws;

    // ---- workspace (byte offsets) ----------------------------------------
    u8_t* xb8 = ws8;                           // [BA*512] x fp8
    u8_t* ht8 = xb8 + (size_t)BA * 512;        // [BA*1024] [h_t | h_p1] fp8
    u8_t* hp8 = ht8 + (size_t)BA * 1024;       // [BA*512] h_p2 fp8
    u8_t* WT  = hp8 + (size_t)BA * 512;
    // phase-2 bf16 aliases (fp8 buffers dead)
    ushort_t* hiddenb = (ushort_t*)xb8;                         // BA*256 ush
    ushort_t* kvq     = (ushort_t*)ht8;                         // BA*192 ush
    ushort_t* applied = (ushort_t*)(ht8 + (size_t)BA * 384);    // BA*128 ush

    u8_t* Bg1   = WT;                      // 1024*512 fp8 [Wt1^T ; Wp1^T]
    u8_t* Wp2t8 = Bg1 + 1024 * 512;        // 512*512 fp8
    u8_t* Dt8   = Wp2t8 + 512 * 512;       // 128*1024 fp8 [Wt2^T | -Wp3^T]
    ushort_t* Wkvq = (ushort_t*)(Dt8 + 128 * 1024);  // 256*256 bf16
    ushort_t* Wct  = Wkvq + 256 * 256;     // 256*384 bf16
    ushort_t* W2t  = Wct  + 256 * 384;     // 128*256 bf16
    float* g1bias = (float*)(W2t + 128 * 256);
    float* pbias  = g1bias + 1024;
    float* cbias  = pbias + 256;
    float* iimp   = cbias + 128;           // BB*AA floats

    const dim3 blk(256);
    const int BIG = 1 << 30;

    // ---- weight prep ------------------------------------------------------
    transpose_w_fp8<<<1024, blk, 0, stream>>>(Wt1, Bg1,             512, 512, 512);
    transpose_w_fp8<<<1024, blk, 0, stream>>>(Wp1, Bg1 + 512 * 512, 512, 512, 512);
    transpose_w_fp8<<<1024, blk, 0, stream>>>(Wp2, Wp2t8, 512, 512, 512);
    transpose_wk_fp8<<<256, blk, 0, stream>>>(Wt2, Dt8, 512, 128, 1024, 0,    1.f);
    transpose_wk_fp8<<<256, blk, 0, stream>>>(Wp3, Dt8, 512, 128, 1024, 512, -1.f);
    transpose_w<<<32,  blk, 0, stream>>>(Wk, Wkvq + 0 * 256,   256, 32, 32);
    transpose_w<<<32,  blk, 0, stream>>>(Wq, Wkvq + 32 * 256,  256, 32, 32);
    transpose_w<<<128, blk, 0, stream>>>(Wv, Wkvq + 64 * 256,  256, 128, 128);
    transpose_w<<<64,  blk, 0, stream>>>(Wk, Wkvq + 192 * 256, 256, 0, 64);   // zero pad
    transpose_w<<<384, blk, 0, stream>>>(Wc, Wct, 384, 256, 256);
    transpose_w<<<128, blk, 0, stream>>>(W2, W2t, 256, 64, 128);
    pack_cat2<<<4, 256, 0, stream>>>(bt1, bp1, g1bias);
    pack_bias<<<1, 256, 0, stream>>>(bk, bq, bv, pbias);
    make_cbias<<<1, 128, 0, stream>>>(bt2, bp3, cbias);

    // ---- phase 1: predictor branch (fp8) ----------------------------------
    conv_f32_fp8<<<65536, blk, 0, stream>>>(x, xb8);
    // [h_t | h_p1] = relu(x @ [Wt1|Wp1] + [bt1|bp1])
    gemm8p_fp8<true><<<2048, 512, 0, stream>>>(
        xb8, 512, xb8, 512, BIG, Bg1, g1bias, ht8, 1024, 512, 2, 64);
    // hidden -> bf16 (xb8 dead)
    conv_f32_bf16<<<32768, blk, 0, stream>>>(hidden, hiddenb);
    // h_p2 = relu(h_p1 @ Wp2 + bp2)
    gemm8p_fp8<true><<<1024, 512, 0, stream>>>(
        ht8 + 512, 1024, ht8 + 512, 1024, BIG, Wp2t8, bp2, hp8, 512, 512, 1, 64);
    // fused: diff = [h_t|h_p2]@[Wt2;-Wp3]+cbias -> rowsq -> softmax -> iimp
    gemm_mfma_fp8_mse<<<1024, blk, 0, stream>>>(
        ht8, 1024, hp8, 512, 512, Dt8, cbias, 1024, iimp);

    // ---- phase 2: communicate (bf16) ---------------------------------------
    // kvq = hidden @ [Wk|Wq|Wv] + pbias  (N=192)
    gemm_mfma<<<2048, blk, 0, stream>>>(
        hiddenb, 256, Wkvq, pbias, kvq, 192, 192, 256, 1);
    attn_apply<<<BB, blk, 0, stream>>>(kvq, Wa, ba, iimp, applied);

    // ---- phase 3: combine + output head (fully fused, bf16) ----------------
    gemm8p<true, true><<<512, 512, 0, stream>>>(
        applied, 128, hiddenb, 256, 128, Wct, bc, (ushort_t*)out, 64, 384, 0, 64, W2t, b2);
}